// Round 2
// baseline (310.917 us; speedup 1.0000x reference)
//
#include <hip/hip_runtime.h>

#define EPS 0.01f
#define TX 128
#define TY 32
#define NTHREADS 256
#define HALO_W (TX + 2)      // 130
#define HALO_H (TY + 2)      // 34
#define LDS_STRIDE (TX + 4)  // 132 -> rows offset by 4 banks, compute reads are stride-1

__global__ __launch_bounds__(NTHREADS) void DetectionHead_nms_kernel(
    const float* __restrict__ seg, float* __restrict__ xnms,
    float* __restrict__ segcopy, int B, int H, int W) {
  __shared__ float xs[HALO_H][LDS_STRIDE];

  const int b = blockIdx.z;
  const int row0 = blockIdx.y * TY;
  const int col0 = blockIdx.x * TX;
  const int tid = threadIdx.x;
  const size_t HW = (size_t)H * W;

  const float* seg0 = seg + (size_t)b * 2 * HW;
  const float* seg1 = seg0 + HW;
  float* cp0 = segcopy + (size_t)b * 2 * HW;
  float* cp1 = cp0 + HW;
  float* xout = xnms + (size_t)b * HW;

  // Cooperative halo load: compute x = s1 - s0 - eps into LDS.
  // OOB elements -> 0 (zero-padding is absorbed by the max's 0 seed).
  // Fused copy: interior elements (owned by exactly this tile) write the
  // segmentation passthrough output from the same loads (L1/L2 hot).
  for (int idx = tid; idx < HALO_H * HALO_W; idx += NTHREADS) {
    int r = idx / HALO_W;
    int c = idx - r * HALO_W;
    int gi = row0 + r - 1;
    int gj = col0 + c - 1;
    float x = 0.0f;
    if (gi >= 0 && gi < H && gj >= 0 && gj < W) {
      size_t g = (size_t)gi * W + gj;
      float s0 = seg0[g];
      float s1 = seg1[g];
      x = s1 - s0 - EPS;
      if (r >= 1 && r <= TY && c >= 1 && c <= TX) {
        cp0[g] = s0;
        cp1[g] = s1;
      }
    }
    xs[r][c] = x;
  }
  __syncthreads();

  // Each thread computes TX*TY/NTHREADS = 16 output pixels.
  for (int k = 0; k < (TX * TY) / NTHREADS; ++k) {
    int pix = tid + k * NTHREADS;
    int li = pix / TX;        // TX=128 pow2 -> shifts
    int lj = pix & (TX - 1);
    int r = li + 1, c = lj + 1;
    float x = xs[r][c];
    float m = 0.0f;           // seed = the jnp.zeros init (also covers relu + padding)
    m = fmaxf(m, xs[r - 1][c - 1]);
    m = fmaxf(m, xs[r - 1][c    ]);
    m = fmaxf(m, xs[r - 1][c + 1]);
    m = fmaxf(m, xs[r    ][c - 1]);
    m = fmaxf(m, xs[r    ][c + 1]);
    m = fmaxf(m, xs[r + 1][c - 1]);
    m = fmaxf(m, xs[r + 1][c    ]);
    m = fmaxf(m, xs[r + 1][c + 1]);
    xout[(size_t)(row0 + li) * W + (col0 + lj)] = (x > m) ? x : 0.0f;
  }
}

extern "C" void kernel_launch(void* const* d_in, const int* in_sizes, int n_in,
                              void* d_out, int out_size, void* d_ws, size_t ws_size,
                              hipStream_t stream) {
  const int B = 16, H = 1024, W = 1024;
  const float* seg = (const float*)d_in[0];
  float* out = (float*)d_out;
  float* xnms = out;                               // [B,H,W]
  float* segcopy = out + (size_t)B * H * W;        // [B,2,H,W]

  dim3 grid(W / TX, H / TY, B);                    // (8, 32, 16) = 4096 blocks
  DetectionHead_nms_kernel<<<grid, NTHREADS, 0, stream>>>(seg, xnms, segcopy, B, H, W);
}